// Round 1
// baseline (2933.971 us; speedup 1.0000x reference)
//
#include <hip/hip_runtime.h>

// ============================================================================
// Tatt: temp construction (analytic roll-collapse) -> 3x gated GCN (f16 MFMA
// GEMM + banded A-mul + tanh*sigmoid) -> Conv1d(k=577) as implicit-im2col f16
// MFMA GEMM with split-K=6 -> reduce+transpose epilogue.
//
// Dims: B=32, T1=288, T3=864, N=H=325 (pad K->352 "IPAD", pad N->384 "NPAD"),
// KSIZE=577. Conv GEMM: M=9216, N=384(pad), Kflat=577*352=203104 (pad 203136).
//
// R1: CONV_SPLITS 2->6. Conv grid was 432 blocks (1.7 blocks/CU, 20%
// occupancy -> barrier-drain exposed, 654 TF). 1296 blocks hits the
// LDS/VGPR-limited 5 blocks/CU (20 waves). 6 f32 partial slices
// (84,934,656 B) exactly fill the aliased S1+S2 region.
// ============================================================================

typedef _Float16 half8 __attribute__((ext_vector_type(8)));
typedef float floatx4 __attribute__((ext_vector_type(4)));

#define DEV __device__ __forceinline__
#define AS1 __attribute__((address_space(1)))
#define AS3 __attribute__((address_space(3)))

constexpr int IPAD = 352;                 // padded inner (sensor) dim
constexpr int NPAD = 384;                 // padded outer (channel) dim
constexpr int MGCN = 32 * 864;            // 27648
constexpr int MCONV = 32 * 288;           // 9216
constexpr int KCONV_PAD = 203136;         // 3174 * 64  (>= 577*352 = 203104)
constexpr int CH_CONV = KCONV_PAD / 64;   // 3174
constexpr int CONV_SPLITS = 6;
constexpr int CH_SPLIT = CH_CONV / CONV_SPLITS;  // 529

// ---- workspace layout (bytes) ----
constexpr size_t OFF_XG = 0;                                   // f16 [27649][352]
constexpr size_t SZ_XG_AL = 19465216;                          // 27649*352*2 = 19464896, aligned
constexpr size_t SZ_S = (size_t)MGCN * NPAD * 4;               // 42467328
constexpr size_t OFF_S1 = OFF_XG + SZ_XG_AL;
constexpr size_t OFF_S2 = OFF_S1 + SZ_S;
constexpr size_t OFF_WG = OFF_S2 + SZ_S;                       // 6 * [384][384] f16
constexpr size_t SZ_WG = 6ull * NPAD * NPAD * 2;               // 1769472
constexpr size_t OFF_WCONV = OFF_WG + SZ_WG;                   // [384][203136] f16
constexpr size_t OFF_CPART = OFF_S1;                           // alias (6 slices of [9216][384] f32)
// total = OFF_WCONV + 384*203136*2 = 262,177,792 bytes

DEV void gload16(const void* g, void* l) {
    __builtin_amdgcn_global_load_lds((const AS1 void*)g, (AS3 void*)l, 16, 0, 0);
}

// ---------------------------------------------------------------------------
// temp:  Xg[b*864+m][i] = (m in [288,576)) ? IF[b][i][m-288]
//                        : x[(m + s_b + 1728) % 2016][i],   0 for i>=325
// ---------------------------------------------------------------------------
__global__ void k_temp(const float* __restrict__ IF, const float* __restrict__ x,
                       const int* __restrict__ week, const int* __restrict__ hour,
                       _Float16* __restrict__ Xg) {
    int idx = blockIdx.x * 256 + threadIdx.x;       // over 27648*352
    if (idx >= MGCN * IPAD) return;
    int i  = idx % IPAD;
    int mm = idx / IPAD;
    int m  = mm % 864, b = mm / 864;
    float v = 0.f;
    if (i < 325) {
        if (m >= 288 && m < 576) {
            v = IF[((size_t)b * 325 + i) * 288 + (m - 288)];
        } else {
            int s  = week[b] * 288 + hour[b];
            int tm = (m + s + 1728) % 2016;
            v = x[(size_t)tm * 325 + i];
        }
    }
    Xg[(size_t)mm * IPAD + i] = (_Float16)v;
}

// ---------------------------------------------------------------------------
// pack 6 GCN weights, transposed + zero-padded:  Wg[l][o][d] = w_l[d*325+o]
// ---------------------------------------------------------------------------
__global__ void k_pack_gcn(const float* w0, const float* w1, const float* w2,
                           const float* w3, const float* w4, const float* w5,
                           _Float16* __restrict__ Wg) {
    int idx = blockIdx.x * 256 + threadIdx.x;       // 6*384*384
    int d = idx % NPAD;
    int o = (idx / NPAD) % NPAD;
    int l = idx / (NPAD * NPAD);
    const float* w = l == 0 ? w0 : l == 1 ? w1 : l == 2 ? w2 : l == 3 ? w3 : l == 4 ? w4 : w5;
    float v = (o < 325 && d < 325) ? w[d * 325 + o] : 0.f;
    Wg[(size_t)idx] = (_Float16)v;
}

// ---------------------------------------------------------------------------
// pack conv weights:  Wc[o][k*352+i] = conv_w[o][i][k]  (zero-padded)
// 32x32 LDS-transpose tiles: read coalesced along k, write coalesced along i.
// ---------------------------------------------------------------------------
__global__ void k_pack_conv(const float* __restrict__ cw, _Float16* __restrict__ Wc) {
    __shared__ float tile[32][33];
    int o = blockIdx.x, i0 = blockIdx.y * 32, k0 = blockIdx.z * 32;
    int t = threadIdx.x;
    int c = t & 31, r4 = t >> 5;
#pragma unroll
    for (int p = 0; p < 4; ++p) {
        int ii = r4 * 4 + p;
        int i = i0 + ii, k = k0 + c;
        float v = 0.f;
        if (o < 325 && i < 325 && k < 577) v = cw[((size_t)o * 325 + i) * 577 + k];
        tile[ii][c] = v;
    }
    __syncthreads();
#pragma unroll
    for (int p = 0; p < 4; ++p) {
        int kk = r4 * 4 + p;
        int k = k0 + kk, i = i0 + c;
        int kidx = k * IPAD + i;
        if (kidx < KCONV_PAD) Wc[(size_t)o * KCONV_PAD + kidx] = (_Float16)tile[c][kk];
    }
}

// ---------------------------------------------------------------------------
// f16 MFMA GEMM, 128x128 tile, BK=64, global_load_lds staging with XOR swizzle.
// C[m][n] = sum_K A[m][K] * Bw[n][K]   (Bw packed row-major [n][K])
// CONV: A row address = (m + (m/288)*576)*352 + kidx  (implicit im2col; pure
//       pointer increment of 64 elems per 64-chunk thanks to (k,i) flattening)
// ---------------------------------------------------------------------------
template <bool CONV>
__global__ __launch_bounds__(256) void k_gemm(const _Float16* __restrict__ Xg,
                                              const _Float16* __restrict__ Bw,
                                              float* __restrict__ C,
                                              int bStride, int chunksPerSplit,
                                              int chunksTotal, long long sliceStride) {
    __shared__ _Float16 sA[128 * 64];
    __shared__ _Float16 sB[128 * 64];
    const int t = threadIdx.x;
    const int m0 = blockIdx.x * 128, n0 = blockIdx.y * 128;
    const int bz = blockIdx.z;
    int chunk0 = bz * chunksPerSplit;
    int nch = chunksTotal - chunk0;
    if (nch > chunksPerSplit) nch = chunksPerSplit;
    C += (size_t)bz * (size_t)sliceStride;

    // staging pointers: thread t stages LDS 16B-block (j*256+t); LDS block
    // position (row, c=t&7) holds GLOBAL block (c ^ (row&7))  [XOR swizzle]
    const int rj = t >> 3;
    const int cg = (t & 7) ^ (rj & 7);
    const _Float16* pa[4];
    const _Float16* pb[4];
#pragma unroll
    for (int j = 0; j < 4; ++j) {
        int m = m0 + j * 32 + rj;
        int mrow = CONV ? (m + (m / 288) * 576) : m;
        pa[j] = Xg + (size_t)mrow * IPAD + (size_t)chunk0 * 64 + cg * 8;
        int n = n0 + j * 32 + rj;
        pb[j] = Bw + (size_t)n * bStride + (size_t)chunk0 * 64 + cg * 8;
    }

    const int lane = t & 63, wv = t >> 6;
    const int wm = wv >> 1, wn = wv & 1;            // 2x2 waves of 64x64
    const int r = lane & 15, q = lane >> 4, s8 = r & 7;
    int aRow[4], bRow[4];
#pragma unroll
    for (int i = 0; i < 4; ++i) {
        aRow[i] = (wm * 64 + i * 16 + r) * 64;
        bRow[i] = (wn * 64 + i * 16 + r) * 64;
    }
    const int xk0 = (q ^ s8) * 8;                   // swizzled 16B-block offsets
    const int xk1 = ((q + 4) ^ s8) * 8;

    floatx4 acc[4][4] = {};

    for (int ch = 0; ch < nch; ++ch) {
        __syncthreads();
#pragma unroll
        for (int j = 0; j < 4; ++j) { gload16(pa[j], &sA[(j * 256 + t) * 8]); pa[j] += 64; }
#pragma unroll
        for (int j = 0; j < 4; ++j) { gload16(pb[j], &sB[(j * 256 + t) * 8]); pb[j] += 64; }
        __syncthreads();
#pragma unroll
        for (int kk = 0; kk < 2; ++kk) {
            const int xk = kk ? xk1 : xk0;
            half8 av[4], bv[4];
#pragma unroll
            for (int mi = 0; mi < 4; ++mi) av[mi] = *(const half8*)(sA + aRow[mi] + xk);
#pragma unroll
            for (int ni = 0; ni < 4; ++ni) bv[ni] = *(const half8*)(sB + bRow[ni] + xk);
#pragma unroll
            for (int mi = 0; mi < 4; ++mi)
#pragma unroll
                for (int ni = 0; ni < 4; ++ni)
                    acc[mi][ni] = __builtin_amdgcn_mfma_f32_16x16x32_f16(av[mi], bv[ni],
                                                                         acc[mi][ni], 0, 0, 0);
        }
    }

    // C/D layout: col = lane&15, row = (lane>>4)*4 + reg   [m89-verified]
#pragma unroll
    for (int mi = 0; mi < 4; ++mi)
#pragma unroll
        for (int ni = 0; ni < 4; ++ni) {
            int row = m0 + wm * 64 + mi * 16 + q * 4;
            int col = n0 + wn * 64 + ni * 16 + r;
#pragma unroll
            for (int e = 0; e < 4; ++e)
                C[(size_t)(row + e) * NPAD + col] = acc[mi][ni][e];
        }
}

// ---------------------------------------------------------------------------
// banded D^-1/2 A D^-1/2 (7-diag) + bias + tanh*sigmoid -> f16 Xg (in place)
// ---------------------------------------------------------------------------
__global__ void k_bandact(const float* __restrict__ S1, const float* __restrict__ S2,
                          const float* __restrict__ b1, const float* __restrict__ b2,
                          _Float16* __restrict__ Xg) {
    int bm = blockIdx.x;                            // 0..27647
    int m = bm % 864;
    int dm = (m < 3 ? m : 3) + ((863 - m) < 3 ? (863 - m) : 3) + 1;
    for (int o = threadIdx.x; o < 325; o += 256) {
        float g1 = b1[o], g2 = b2[o];
#pragma unroll
        for (int dn = -3; dn <= 3; ++dn) {
            int n = m + dn;
            if (n < 0 || n > 863) continue;
            int dnd = (n < 3 ? n : 3) + ((863 - n) < 3 ? (863 - n) : 3) + 1;
            float a = rsqrtf((float)(dm * dnd));
            size_t off = (size_t)(bm + dn) * NPAD + o;
            g1 += a * S1[off];
            g2 += a * S2[off];
        }
        float vt = tanhf(g1);
        float vs = 1.f / (1.f + expf(-g2));
        Xg[(size_t)bm * IPAD + o] = (_Float16)(vt * vs);
    }
}

// ---------------------------------------------------------------------------
// reduce split-K slices + conv bias, transpose [m=(b,t)][o] -> out[b][o][t]
// ---------------------------------------------------------------------------
__global__ void k_reduce(const float* __restrict__ Cp, const float* __restrict__ cb,
                         float* __restrict__ out) {
    __shared__ float tile[32][33];
    int b = blockIdx.x, t0 = blockIdx.y * 32, o0 = blockIdx.z * 32;
    int t = threadIdx.x;
    int c = t & 31, r4 = t >> 5;
#pragma unroll
    for (int p = 0; p < 4; ++p) {
        int tt = r4 * 4 + p;
        size_t mrow = (size_t)(b * 288 + t0 + tt) * NPAD + (o0 + c);
        float acc = 0.f;
#pragma unroll
        for (int s = 0; s < CONV_SPLITS; ++s)
            acc += Cp[(size_t)s * MCONV * NPAD + mrow];
        tile[tt][c] = acc;
    }
    __syncthreads();
#pragma unroll
    for (int p = 0; p < 4; ++p) {
        int oo = r4 * 4 + p;
        int o = o0 + oo;
        if (o < 325)
            out[((size_t)b * 325 + o) * 288 + t0 + c] = tile[c][oo] + cb[o];
    }
}

// ---------------------------------------------------------------------------
extern "C" void kernel_launch(void* const* d_in, const int* in_sizes, int n_in,
                              void* d_out, int out_size, void* d_ws, size_t ws_size,
                              hipStream_t stream) {
    const float* IF = (const float*)d_in[0];
    const float* x  = (const float*)d_in[1];
    const float* wg[6] = {(const float*)d_in[2],  (const float*)d_in[4],
                          (const float*)d_in[6],  (const float*)d_in[8],
                          (const float*)d_in[10], (const float*)d_in[12]};
    const float* bg[6] = {(const float*)d_in[3],  (const float*)d_in[5],
                          (const float*)d_in[7],  (const float*)d_in[9],
                          (const float*)d_in[11], (const float*)d_in[13]};
    const float* cw  = (const float*)d_in[14];
    const float* cb  = (const float*)d_in[15];
    const int* week  = (const int*)d_in[16];
    const int* hour  = (const int*)d_in[17];
    float* out = (float*)d_out;

    char* ws = (char*)d_ws;
    _Float16* Xg = (_Float16*)(ws + OFF_XG);
    float* S1    = (float*)(ws + OFF_S1);
    float* S2    = (float*)(ws + OFF_S2);
    _Float16* Wg = (_Float16*)(ws + OFF_WG);
    _Float16* Wc = (_Float16*)(ws + OFF_WCONV);
    float* Cp    = (float*)(ws + OFF_CPART);   // aliases S1/S2 (conv phase only)

    k_pack_gcn<<<(6 * NPAD * NPAD) / 256, 256, 0, stream>>>(wg[0], wg[1], wg[2], wg[3],
                                                            wg[4], wg[5], Wg);
    k_pack_conv<<<dim3(NPAD, 11, 19), 256, 0, stream>>>(cw, Wc);
    k_temp<<<(MGCN * IPAD) / 256, 256, 0, stream>>>(IF, x, week, hour, Xg);

    for (int l = 0; l < 3; ++l) {
        k_gemm<false><<<dim3(MGCN / 128, NPAD / 128, 1), 256, 0, stream>>>(
            Xg, Wg + (size_t)(2 * l) * NPAD * NPAD, S1, NPAD, 6, 6, 0);
        k_gemm<false><<<dim3(MGCN / 128, NPAD / 128, 1), 256, 0, stream>>>(
            Xg, Wg + (size_t)(2 * l + 1) * NPAD * NPAD, S2, NPAD, 6, 6, 0);
        k_bandact<<<MGCN, 256, 0, stream>>>(S1, S2, bg[2 * l], bg[2 * l + 1], Xg);
    }

    k_gemm<true><<<dim3(MCONV / 128, NPAD / 128, CONV_SPLITS), 256, 0, stream>>>(
        Xg, Wc, Cp, KCONV_PAD, CH_SPLIT, CH_CONV, (long long)MCONV * NPAD);

    k_reduce<<<dim3(32, 9, 11), 256, 0, stream>>>(Cp, cb, out);
}

// Round 3
// 2181.594 us; speedup vs baseline: 1.3449x; 1.3449x over previous
//
#include <hip/hip_runtime.h>

// ============================================================================
// Tatt: temp construction (analytic roll-collapse) -> 3x gated GCN (f16 MFMA
// GEMM + banded A-mul + tanh*sigmoid) -> Conv1d(k=577) as implicit-im2col f16
// MFMA GEMM -> reduce+transpose epilogue.
//
// Dims: B=32, T1=288, T3=864, N=H=325 (pad K->352 "IPAD", pad N->384 "NPAD"),
// KSIZE=577. Conv GEMM: M=9216, N=384(pad), Kflat=577*352=203104 (pad 203136).
//
// R2/R3: conv GEMM as k_conv: 256x384 tile (full-N), BK=32, 512 thr
// (8 waves, wave tile 64x192, acc 192 f32/thr), triple-buffered LDS with
// depth-2 counted-vmcnt pipeline. Rationale: 128^2 tiling streams 22.5 GB of
// operand panels from L3 (10.2 TB/s observed -> duration invariant to
// split-K, R1); 256x384 cuts traffic to ~9.3 GB (A slices L2-resident).
// Pair-line XOR-swizzled LDS (2-way max aliasing = free).
// ============================================================================

typedef _Float16 half8 __attribute__((ext_vector_type(8)));
typedef float floatx4 __attribute__((ext_vector_type(4)));

#define DEV __device__ __forceinline__
#define AS1 __attribute__((address_space(1)))
#define AS3 __attribute__((address_space(3)))

constexpr int IPAD = 352;                 // padded inner (sensor) dim
constexpr int NPAD = 384;                 // padded outer (channel) dim
constexpr int MGCN = 32 * 864;            // 27648
constexpr int MCONV = 32 * 288;           // 9216
constexpr int KCONV_PAD = 203136;         // 3174 * 64  (>= 577*352 = 203104)
constexpr int CONV_SPLITS = 6;
constexpr int CH32_TOTAL = KCONV_PAD / 32;           // 6348
constexpr int CH32_SPLIT = CH32_TOTAL / CONV_SPLITS; // 1058

// ---- workspace layout (bytes) ----
constexpr size_t OFF_XG = 0;                                   // f16 [27649][352]
constexpr size_t SZ_XG_AL = 19465216;                          // 27649*352*2, aligned
constexpr size_t SZ_S = (size_t)MGCN * NPAD * 4;               // 42467328
constexpr size_t OFF_S1 = OFF_XG + SZ_XG_AL;
constexpr size_t OFF_S2 = OFF_S1 + SZ_S;
constexpr size_t OFF_WG = OFF_S2 + SZ_S;                       // 6 * [384][384] f16
constexpr size_t SZ_WG = 6ull * NPAD * NPAD * 2;               // 1769472
constexpr size_t OFF_WCONV = OFF_WG + SZ_WG;                   // [384][203136] f16
constexpr size_t OFF_CPART = OFF_S1;                           // alias (6 slices [9216][384] f32)
// total = OFF_WCONV + 384*203136*2 = 262,177,792 bytes

DEV void gload16(const void* g, void* l) {
    __builtin_amdgcn_global_load_lds((const AS1 void*)g, (AS3 void*)l, 16, 0, 0);
}

#define MEMFENCE() asm volatile("" ::: "memory")
#define BARRIER() do { MEMFENCE(); __builtin_amdgcn_s_barrier(); MEMFENCE(); } while (0)

// ---------------------------------------------------------------------------
// temp:  Xg[b*864+m][i] = (m in [288,576)) ? IF[b][i][m-288]
//                        : x[(m + s_b + 1728) % 2016][i],   0 for i>=325
// ---------------------------------------------------------------------------
__global__ void k_temp(const float* __restrict__ IF, const float* __restrict__ x,
                       const int* __restrict__ week, const int* __restrict__ hour,
                       _Float16* __restrict__ Xg) {
    int idx = blockIdx.x * 256 + threadIdx.x;       // over 27648*352
    if (idx >= MGCN * IPAD) return;
    int i  = idx % IPAD;
    int mm = idx / IPAD;
    int m  = mm % 864, b = mm / 864;
    float v = 0.f;
    if (i < 325) {
        if (m >= 288 && m < 576) {
            v = IF[((size_t)b * 325 + i) * 288 + (m - 288)];
        } else {
            int s  = week[b] * 288 + hour[b];
            int tm = (m + s + 1728) % 2016;
            v = x[(size_t)tm * 325 + i];
        }
    }
    Xg[(size_t)mm * IPAD + i] = (_Float16)v;
}

// ---------------------------------------------------------------------------
// pack 6 GCN weights, transposed + zero-padded:  Wg[l][o][d] = w_l[d*325+o]
// ---------------------------------------------------------------------------
__global__ void k_pack_gcn(const float* w0, const float* w1, const float* w2,
                           const float* w3, const float* w4, const float* w5,
                           _Float16* __restrict__ Wg) {
    int idx = blockIdx.x * 256 + threadIdx.x;       // 6*384*384
    int d = idx % NPAD;
    int o = (idx / NPAD) % NPAD;
    int l = idx / (NPAD * NPAD);
    const float* w = l == 0 ? w0 : l == 1 ? w1 : l == 2 ? w2 : l == 3 ? w3 : l == 4 ? w4 : w5;
    float v = (o < 325 && d < 325) ? w[d * 325 + o] : 0.f;
    Wg[(size_t)idx] = (_Float16)v;
}

// ---------------------------------------------------------------------------
// pack conv weights:  Wc[o][k*352+i] = conv_w[o][i][k]  (zero-padded)
// ---------------------------------------------------------------------------
__global__ void k_pack_conv(const float* __restrict__ cw, _Float16* __restrict__ Wc) {
    __shared__ float tile[32][33];
    int o = blockIdx.x, i0 = blockIdx.y * 32, k0 = blockIdx.z * 32;
    int t = threadIdx.x;
    int c = t & 31, r4 = t >> 5;
#pragma unroll
    for (int p = 0; p < 4; ++p) {
        int ii = r4 * 4 + p;
        int i = i0 + ii, k = k0 + c;
        float v = 0.f;
        if (o < 325 && i < 325 && k < 577) v = cw[((size_t)o * 325 + i) * 577 + k];
        tile[ii][c] = v;
    }
    __syncthreads();
#pragma unroll
    for (int p = 0; p < 4; ++p) {
        int kk = r4 * 4 + p;
        int k = k0 + kk, i = i0 + c;
        int kidx = k * IPAD + i;
        if (kidx < KCONV_PAD) Wc[(size_t)o * KCONV_PAD + kidx] = (_Float16)tile[c][kk];
    }
}

// ---------------------------------------------------------------------------
// f16 MFMA GEMM (GCN layers), 128x128 tile, BK=64, global_load_lds + XOR swz.
// C[m][n] = sum_K A[m][K] * Bw[n][K]
// ---------------------------------------------------------------------------
template <bool CONV>
__global__ __launch_bounds__(256) void k_gemm(const _Float16* __restrict__ Xg,
                                              const _Float16* __restrict__ Bw,
                                              float* __restrict__ C,
                                              int bStride, int chunksPerSplit,
                                              int chunksTotal, long long sliceStride) {
    __shared__ _Float16 sA[128 * 64];
    __shared__ _Float16 sB[128 * 64];
    const int t = threadIdx.x;
    const int m0 = blockIdx.x * 128, n0 = blockIdx.y * 128;
    const int bz = blockIdx.z;
    int chunk0 = bz * chunksPerSplit;
    int nch = chunksTotal - chunk0;
    if (nch > chunksPerSplit) nch = chunksPerSplit;
    C += (size_t)bz * (size_t)sliceStride;

    const int rj = t >> 3;
    const int cg = (t & 7) ^ (rj & 7);
    const _Float16* pa[4];
    const _Float16* pb[4];
#pragma unroll
    for (int j = 0; j < 4; ++j) {
        int m = m0 + j * 32 + rj;
        int mrow = CONV ? (m + (m / 288) * 576) : m;
        pa[j] = Xg + (size_t)mrow * IPAD + (size_t)chunk0 * 64 + cg * 8;
        int n = n0 + j * 32 + rj;
        pb[j] = Bw + (size_t)n * bStride + (size_t)chunk0 * 64 + cg * 8;
    }

    const int lane = t & 63, wv = t >> 6;
    const int wm = wv >> 1, wn = wv & 1;            // 2x2 waves of 64x64
    const int r = lane & 15, q = lane >> 4, s8 = r & 7;
    int aRow[4], bRow[4];
#pragma unroll
    for (int i = 0; i < 4; ++i) {
        aRow[i] = (wm * 64 + i * 16 + r) * 64;
        bRow[i] = (wn * 64 + i * 16 + r) * 64;
    }
    const int xk0 = (q ^ s8) * 8;
    const int xk1 = ((q + 4) ^ s8) * 8;

    floatx4 acc[4][4] = {};

    for (int ch = 0; ch < nch; ++ch) {
        __syncthreads();
#pragma unroll
        for (int j = 0; j < 4; ++j) { gload16(pa[j], &sA[(j * 256 + t) * 8]); pa[j] += 64; }
#pragma unroll
        for (int j = 0; j < 4; ++j) { gload16(pb[j], &sB[(j * 256 + t) * 8]); pb[j] += 64; }
        __syncthreads();
#pragma unroll
        for (int kk = 0; kk < 2; ++kk) {
            const int xk = kk ? xk1 : xk0;
            half8 av[4], bv[4];
#pragma unroll
            for (int mi = 0; mi < 4; ++mi) av[mi] = *(const half8*)(sA + aRow[mi] + xk);
#pragma unroll
            for (int ni = 0; ni < 4; ++ni) bv[ni] = *(const half8*)(sB + bRow[ni] + xk);
#pragma unroll
            for (int mi = 0; mi < 4; ++mi)
#pragma unroll
                for (int ni = 0; ni < 4; ++ni)
                    acc[mi][ni] = __builtin_amdgcn_mfma_f32_16x16x32_f16(av[mi], bv[ni],
                                                                         acc[mi][ni], 0, 0, 0);
        }
    }

#pragma unroll
    for (int mi = 0; mi < 4; ++mi)
#pragma unroll
        for (int ni = 0; ni < 4; ++ni) {
            int row = m0 + wm * 64 + mi * 16 + q * 4;
            int col = n0 + wn * 64 + ni * 16 + r;
#pragma unroll
            for (int e = 0; e < 4; ++e)
                C[(size_t)(row + e) * NPAD + col] = acc[mi][ni][e];
        }
}

// ---------------------------------------------------------------------------
// conv GEMM: 256x384 tile (full N), BK=32, 512 threads = 8 waves (4M x 2N,
// wave tile 64x192). Triple-buffered LDS (3 x 40 KB), depth-2 prefetch with
// counted s_waitcnt vmcnt(10) -- loads for chunks c+1,c+2 stay in flight
// across barriers.
//
// LDS layout per buffer: A = 128 "pair-lines" (rows 2j,2j+1; 8 x 16B blocks,
// 128 B/line) then B = 192 pair-lines. Slot (j,cc) holds global block
// g = cc ^ (j&7), g = (rowparity<<2)|kblk. Frag reads: stepping 16 rows = 8
// lines keeps j&7 -> offset = base + idx*1024 immediates; 2-way bank aliasing
// max (free, m136). LDS dest is wave-uniform base + lane*16 (m104-safe).
// ---------------------------------------------------------------------------
__global__ __launch_bounds__(512, 2) void k_conv(const _Float16* __restrict__ Xg,
                                                 const _Float16* __restrict__ Wc,
                                                 float* __restrict__ C) {
    __shared__ _Float16 lds[3 * 20480];             // 3 x 40960 B = 122880 B
    const int t = threadIdx.x;
    const int m0 = blockIdx.x * 256;
    const int z  = blockIdx.y;
    const int chunk0 = z * CH32_SPLIT;
    const int nch = CH32_SPLIT;                     // 6348 = 6*1058 exact
    C += (size_t)z * MCONV * NPAD;

    // ---- staging: 5 slots/thread (2 A + 3 B) ----
    const _Float16* src[5];
    int ldsoff[5];                                  // byte offset within a buffer
#pragma unroll
    for (int p = 0; p < 2; ++p) {
        int s = t + p * 512;                        // A slot 0..1023
        int j = s >> 3, cc = s & 7;
        int g = cc ^ (j & 7);
        int m = m0 + 2 * j + (g >> 2);
        int mrow = m + (m / 288) * 576;             // implicit im2col
        src[p] = Xg + (size_t)mrow * IPAD + (size_t)chunk0 * 32 + (g & 3) * 8;
        ldsoff[p] = s * 16;
    }
#pragma unroll
    for (int p = 0; p < 3; ++p) {
        int s = t + p * 512;                        // B slot 0..1535
        int j = s >> 3, cc = s & 7;
        int g = cc ^ (j & 7);
        int n = 2 * j + (g >> 2);
        src[2 + p] = Wc + (size_t)n * KCONV_PAD + (size_t)chunk0 * 32 + (g & 3) * 8;
        ldsoff[2 + p] = 16384 + s * 16;
    }

    // ---- fragment read offsets ----
    const int lane = t & 63, wv = t >> 6;
    const int wm = wv >> 1, wn = wv & 1;            // 4M x 2N waves
    const int r = lane & 15, q = lane >> 4;
    int row_a = wm * 64 + r;
    int aoff0 = (row_a >> 1) * 128 + ((((row_a & 1) << 2) | q) ^ ((row_a >> 1) & 7)) * 16;
    int row_b = wn * 192 + r;
    int boff0 = 16384 + (row_b >> 1) * 128 +
                ((((row_b & 1) << 2) | q) ^ ((row_b >> 1) & 7)) * 16;

    floatx4 acc[4][12] = {};

    auto stage = [&](int lc, int buf) {
        char* dst = (char*)lds + buf * 40960;
        size_t adv = (size_t)lc * 32;               // 32 halfs = 64 B per chunk
#pragma unroll
        for (int p = 0; p < 5; ++p)
            gload16(src[p] + adv, dst + ldsoff[p]);
    };

    // prologue: chunks 0,1 in flight
    stage(0, 0);
    stage(1, 1);

    int buf = 0;
    for (int lc = 0; lc < nch; ++lc) {
        int pre = lc + 2;  if (pre > nch - 1) pre = nch - 1;     // tail: dummy re-read
        int pbuf = buf + 2; if (pbuf >= 3) pbuf -= 3;
        stage(pre, pbuf);                            // issue loads for lc+2
        asm volatile("s_waitcnt vmcnt(10)" ::: "memory");        // chunk lc landed
        BARRIER();
        const char* cb = (const char*)lds + buf * 40960;
        half8 av[4];
#pragma unroll
        for (int mi = 0; mi < 4; ++mi)
            av[mi] = *(const half8*)(cb + aoff0 + mi * 1024);
#pragma unroll
        for (int ni = 0; ni < 12; ++ni) {
            half8 bv = *(const half8*)(cb + boff0 + ni * 1024);
#pragma unroll
            for (int mi = 0; mi < 4; ++mi)
                acc[mi][ni] = __builtin_amdgcn_mfma_f32_16x16x32_f16(av[mi], bv,
                                                                     acc[mi][ni], 0, 0, 0);
        }
        BARRIER();                                   // all reads of buf done
        buf = (buf + 1 == 3) ? 0 : buf + 1;
    }
    asm volatile("s_waitcnt vmcnt(0)" ::: "memory");

    // C/D layout: col = lane&15, row = (lane>>4)*4 + reg   [m89-verified]
#pragma unroll
    for (int mi = 0; mi < 4; ++mi)
#pragma unroll
        for (int ni = 0; ni < 12; ++ni) {
            int row = m0 + wm * 64 + mi * 16 + q * 4;
            int col = wn * 192 + ni * 16 + r;
#pragma unroll
            for (int e = 0; e < 4; ++e)
                C[(size_t)(row + e) * NPAD + col] = acc[mi][ni][e];
        }
}

// ---------------------------------------------------------------------------
// banded D^-1/2 A D^-1/2 (7-diag) + bias + tanh*sigmoid -> f16 Xg (in place)
// ---------------------------------------------------------------------------
__global__ void k_bandact(const float* __restrict__ S1, const float* __restrict__ S2,
                          const float* __restrict__ b1, const float* __restrict__ b2,
                          _Float16* __restrict__ Xg) {
    int bm = blockIdx.x;                            // 0..27647
    int m = bm % 864;
    int dm = (m < 3 ? m : 3) + ((863 - m) < 3 ? (863 - m) : 3) + 1;
    for (int o = threadIdx.x; o < 325; o += 256) {
        float g1 = b1[o], g2 = b2[o];
#pragma unroll
        for (int dn = -3; dn <= 3; ++dn) {
            int n = m + dn;
            if (n < 0 || n > 863) continue;
            int dnd = (n < 3 ? n : 3) + ((863 - n) < 3 ? (863 - n) : 3) + 1;
            float a = rsqrtf((float)(dm * dnd));
            size_t off = (size_t)(bm + dn) * NPAD + o;
            g1 += a * S1[off];
            g2 += a * S2[off];
        }
        float vt = tanhf(g1);
        float vs = 1.f / (1.f + expf(-g2));
        Xg[(size_t)bm * IPAD + o] = (_Float16)(vt * vs);
    }
}

// ---------------------------------------------------------------------------
// reduce split-K slices + conv bias, transpose [m=(b,t)][o] -> out[b][o][t]
// ---------------------------------------------------------------------------
__global__ void k_reduce(const float* __restrict__ Cp, const float* __restrict__ cb,
                         float* __restrict__ out) {
    __shared__ float tile[32][33];
    int b = blockIdx.x, t0 = blockIdx.y * 32, o0 = blockIdx.z * 32;
    int t = threadIdx.x;
    int c = t & 31, r4 = t >> 5;
#pragma unroll
    for (int p = 0; p < 4; ++p) {
        int tt = r4 * 4 + p;
        size_t mrow = (size_t)(b * 288 + t0 + tt) * NPAD + (o0 + c);
        float acc = 0.f;
#pragma unroll
        for (int s = 0; s < CONV_SPLITS; ++s)
            acc += Cp[(size_t)s * MCONV * NPAD + mrow];
        tile[tt][c] = acc;
    }
    __syncthreads();
#pragma unroll
    for (int p = 0; p < 4; ++p) {
        int oo = r4 * 4 + p;
        int o = o0 + oo;
        if (o < 325)
            out[((size_t)b * 325 + o) * 288 + t0 + c] = tile[c][oo] + cb[o];
    }
}

// ---------------------------------------------------------------------------
extern "C" void kernel_launch(void* const* d_in, const int* in_sizes, int n_in,
                              void* d_out, int out_size, void* d_ws, size_t ws_size,
                              hipStream_t stream) {
    const float* IF = (const float*)d_in[0];
    const float* x  = (const float*)d_in[1];
    const float* wg[6] = {(const float*)d_in[2],  (const float*)d_in[4],
                          (const float*)d_in[6],  (const float*)d_in[8],
                          (const float*)d_in[10], (const float*)d_in[12]};
    const float* bg[6] = {(const float*)d_in[3],  (const float*)d_in[5],
                          (const float*)d_in[7],  (const float*)d_in[9],
                          (const float*)d_in[11], (const float*)d_in[13]};
    const float* cw  = (const float*)d_in[14];
    const float* cb  = (const float*)d_in[15];
    const int* week  = (const int*)d_in[16];
    const int* hour  = (const int*)d_in[17];
    float* out = (float*)d_out;

    char* ws = (char*)d_ws;
    _Float16* Xg = (_Float16*)(ws + OFF_XG);
    float* S1    = (float*)(ws + OFF_S1);
    float* S2    = (float*)(ws + OFF_S2);
    _Float16* Wg = (_Float16*)(ws + OFF_WG);
    _Float16* Wc = (_Float16*)(ws + OFF_WCONV);
    float* Cp    = (float*)(ws + OFF_CPART);   // aliases S1/S2 (conv phase only)

    k_pack_gcn<<<(6 * NPAD * NPAD) / 256, 256, 0, stream>>>(wg[0], wg[1], wg[2], wg[3],
                                                            wg[4], wg[5], Wg);
    k_pack_conv<<<dim3(NPAD, 11, 19), 256, 0, stream>>>(cw, Wc);
    k_temp<<<(MGCN * IPAD) / 256, 256, 0, stream>>>(IF, x, week, hour, Xg);

    for (int l = 0; l < 3; ++l) {
        k_gemm<false><<<dim3(MGCN / 128, NPAD / 128, 1), 256, 0, stream>>>(
            Xg, Wg + (size_t)(2 * l) * NPAD * NPAD, S1, NPAD, 6, 6, 0);
        k_gemm<false><<<dim3(MGCN / 128, NPAD / 128, 1), 256, 0, stream>>>(
            Xg, Wg + (size_t)(2 * l + 1) * NPAD * NPAD, S2, NPAD, 6, 6, 0);
        k_bandact<<<MGCN, 256, 0, stream>>>(S1, S2, bg[2 * l], bg[2 * l + 1], Xg);
    }

    k_conv<<<dim3(MCONV / 256, CONV_SPLITS), 512, 0, stream>>>(Xg, Wc, Cp);

    k_reduce<<<dim3(32, 9, 11), 256, 0, stream>>>(Cp, cb, out);
}

// Round 4
// 2040.531 us; speedup vs baseline: 1.4378x; 1.0691x over previous
//
#include <hip/hip_runtime.h>

// ============================================================================
// Tatt: temp construction (analytic roll-collapse) -> 3x gated GCN (fused-pair
// f16 MFMA GEMM N=768 + banded A-mul + tanh*sigmoid) -> Conv1d(k=577) as
// implicit-im2col f16 MFMA GEMM (split-K=7, atomic reduce) -> bias+transpose.
//
// Dims: B=32, T1=288, T3=864, N=H=325 (pad K->352 "IPAD", pad N->384 "NPAD"),
// KSIZE=577. Conv GEMM: M=9216, N=384(pad), Kflat=577*352=203104 (pad 203136).
//
// R4: (a) conv split-K 6->7 = 252 blocks (was 216 on 256 CUs: 40 CUs idle);
// partials via unsafeAtomicAdd into one zeroed f32 buffer (7 slices wouldn't
// fit workspace). (b) GCN pairs share A -> fused N=768 GEMM (3 launches not
// 6, A traffic halved); fused S[27648][768] = exactly old S1+S2 region.
// ============================================================================

typedef _Float16 half8 __attribute__((ext_vector_type(8)));
typedef float floatx4 __attribute__((ext_vector_type(4)));

#define DEV __device__ __forceinline__
#define AS1 __attribute__((address_space(1)))
#define AS3 __attribute__((address_space(3)))

constexpr int IPAD = 352;                 // padded inner (sensor) dim
constexpr int NPAD = 384;                 // padded outer (channel) dim
constexpr int NFUSE = 768;                // fused GCN output (two gates)
constexpr int MGCN = 32 * 864;            // 27648
constexpr int MCONV = 32 * 288;           // 9216
constexpr int KCONV_PAD = 203136;         // 3174 * 64  (>= 577*352 = 203104)
constexpr int CONV_SPLITS = 7;
constexpr int CH32_TOTAL = KCONV_PAD / 32;           // 6348
constexpr int CH32_PER = 907;                        // ceil(6348/7); last split 906

// ---- workspace layout (bytes) ----
constexpr size_t OFF_XG = 0;                                   // f16 [27649][352]
constexpr size_t SZ_XG_AL = 19465216;                          // 27649*352*2, aligned
constexpr size_t OFF_S = OFF_XG + SZ_XG_AL;                    // f32 [27648][768] fused
constexpr size_t SZ_S = (size_t)MGCN * NFUSE * 4;              // 84934656
constexpr size_t OFF_WG = OFF_S + SZ_S;                        // 6 * [384][384] f16
constexpr size_t SZ_WG = 6ull * NPAD * NPAD * 2;               // 1769472
constexpr size_t OFF_WCONV = OFF_WG + SZ_WG;                   // [384][203136] f16
constexpr size_t OFF_CPART = OFF_S;                            // alias: f32 [9216][384]
// total = OFF_WCONV + 384*203136*2 = 262,177,792 bytes

DEV void gload16(const void* g, void* l) {
    __builtin_amdgcn_global_load_lds((const AS1 void*)g, (AS3 void*)l, 16, 0, 0);
}

#define MEMFENCE() asm volatile("" ::: "memory")
#define BARRIER() do { MEMFENCE(); __builtin_amdgcn_s_barrier(); MEMFENCE(); } while (0)

// ---------------------------------------------------------------------------
// temp:  Xg[b*864+m][i] = (m in [288,576)) ? IF[b][i][m-288]
//                        : x[(m + s_b + 1728) % 2016][i],   0 for i>=325
// ---------------------------------------------------------------------------
__global__ void k_temp(const float* __restrict__ IF, const float* __restrict__ x,
                       const int* __restrict__ week, const int* __restrict__ hour,
                       _Float16* __restrict__ Xg) {
    int idx = blockIdx.x * 256 + threadIdx.x;       // over 27648*352
    if (idx >= MGCN * IPAD) return;
    int i  = idx % IPAD;
    int mm = idx / IPAD;
    int m  = mm % 864, b = mm / 864;
    float v = 0.f;
    if (i < 325) {
        if (m >= 288 && m < 576) {
            v = IF[((size_t)b * 325 + i) * 288 + (m - 288)];
        } else {
            int s  = week[b] * 288 + hour[b];
            int tm = (m + s + 1728) % 2016;
            v = x[(size_t)tm * 325 + i];
        }
    }
    Xg[(size_t)mm * IPAD + i] = (_Float16)v;
}

// ---------------------------------------------------------------------------
// pack 6 GCN weights, transposed + zero-padded:  Wg[l][o][d] = w_l[d*325+o]
// (pairs 2l,2l+1 are contiguous -> fused GEMM sees one [768][384] B panel)
// ---------------------------------------------------------------------------
__global__ void k_pack_gcn(const float* w0, const float* w1, const float* w2,
                           const float* w3, const float* w4, const float* w5,
                           _Float16* __restrict__ Wg) {
    int idx = blockIdx.x * 256 + threadIdx.x;       // 6*384*384
    int d = idx % NPAD;
    int o = (idx / NPAD) % NPAD;
    int l = idx / (NPAD * NPAD);
    const float* w = l == 0 ? w0 : l == 1 ? w1 : l == 2 ? w2 : l == 3 ? w3 : l == 4 ? w4 : w5;
    float v = (o < 325 && d < 325) ? w[d * 325 + o] : 0.f;
    Wg[(size_t)idx] = (_Float16)v;
}

// ---------------------------------------------------------------------------
// pack conv weights:  Wc[o][k*352+i] = conv_w[o][i][k]  (zero-padded)
// ---------------------------------------------------------------------------
__global__ void k_pack_conv(const float* __restrict__ cw, _Float16* __restrict__ Wc) {
    __shared__ float tile[32][33];
    int o = blockIdx.x, i0 = blockIdx.y * 32, k0 = blockIdx.z * 32;
    int t = threadIdx.x;
    int c = t & 31, r4 = t >> 5;
#pragma unroll
    for (int p = 0; p < 4; ++p) {
        int ii = r4 * 4 + p;
        int i = i0 + ii, k = k0 + c;
        float v = 0.f;
        if (o < 325 && i < 325 && k < 577) v = cw[((size_t)o * 325 + i) * 577 + k];
        tile[ii][c] = v;
    }
    __syncthreads();
#pragma unroll
    for (int p = 0; p < 4; ++p) {
        int kk = r4 * 4 + p;
        int k = k0 + kk, i = i0 + c;
        int kidx = k * IPAD + i;
        if (kidx < KCONV_PAD) Wc[(size_t)o * KCONV_PAD + kidx] = (_Float16)tile[c][kk];
    }
}

// ---------------------------------------------------------------------------
// fused GCN GEMM: 128x128 tile over [27648][768], BK=64 x 6 chunks (K padded
// 384; A-overrun rows hit zero B cols -> contributes 0). global_load_lds +
// XOR swizzle. C[m][n] = sum_K A[m][K] * Bw[n][K], C stride = 768.
// ---------------------------------------------------------------------------
__global__ __launch_bounds__(256) void k_gemm(const _Float16* __restrict__ Xg,
                                              const _Float16* __restrict__ Bw,
                                              float* __restrict__ C) {
    __shared__ _Float16 sA[128 * 64];
    __shared__ _Float16 sB[128 * 64];
    const int t = threadIdx.x;
    const int m0 = blockIdx.x * 128, n0 = blockIdx.y * 128;

    const int rj = t >> 3;
    const int cg = (t & 7) ^ (rj & 7);
    const _Float16* pa[4];
    const _Float16* pb[4];
#pragma unroll
    for (int j = 0; j < 4; ++j) {
        int m = m0 + j * 32 + rj;
        pa[j] = Xg + (size_t)m * IPAD + cg * 8;
        int n = n0 + j * 32 + rj;
        pb[j] = Bw + (size_t)n * NPAD + cg * 8;
    }

    const int lane = t & 63, wv = t >> 6;
    const int wm = wv >> 1, wn = wv & 1;            // 2x2 waves of 64x64
    const int r = lane & 15, q = lane >> 4, s8 = r & 7;
    int aRow[4], bRow[4];
#pragma unroll
    for (int i = 0; i < 4; ++i) {
        aRow[i] = (wm * 64 + i * 16 + r) * 64;
        bRow[i] = (wn * 64 + i * 16 + r) * 64;
    }
    const int xk0 = (q ^ s8) * 8;
    const int xk1 = ((q + 4) ^ s8) * 8;

    floatx4 acc[4][4] = {};

    for (int ch = 0; ch < 6; ++ch) {
        __syncthreads();
#pragma unroll
        for (int j = 0; j < 4; ++j) { gload16(pa[j], &sA[(j * 256 + t) * 8]); pa[j] += 64; }
#pragma unroll
        for (int j = 0; j < 4; ++j) { gload16(pb[j], &sB[(j * 256 + t) * 8]); pb[j] += 64; }
        __syncthreads();
#pragma unroll
        for (int kk = 0; kk < 2; ++kk) {
            const int xk = kk ? xk1 : xk0;
            half8 av[4], bv[4];
#pragma unroll
            for (int mi = 0; mi < 4; ++mi) av[mi] = *(const half8*)(sA + aRow[mi] + xk);
#pragma unroll
            for (int ni = 0; ni < 4; ++ni) bv[ni] = *(const half8*)(sB + bRow[ni] + xk);
#pragma unroll
            for (int mi = 0; mi < 4; ++mi)
#pragma unroll
                for (int ni = 0; ni < 4; ++ni)
                    acc[mi][ni] = __builtin_amdgcn_mfma_f32_16x16x32_f16(av[mi], bv[ni],
                                                                         acc[mi][ni], 0, 0, 0);
        }
    }

    // C/D layout: col = lane&15, row = (lane>>4)*4 + reg   [m89-verified]
#pragma unroll
    for (int mi = 0; mi < 4; ++mi)
#pragma unroll
        for (int ni = 0; ni < 4; ++ni) {
            int row = m0 + wm * 64 + mi * 16 + q * 4;
            int col = n0 + wn * 64 + ni * 16 + r;
#pragma unroll
            for (int e = 0; e < 4; ++e)
                C[(size_t)(row + e) * NFUSE + col] = acc[mi][ni][e];
        }
}

// ---------------------------------------------------------------------------
// conv GEMM: 256x384 tile (full N), BK=32, 512 threads = 8 waves (4M x 2N,
// wave tile 64x192). Triple-buffered LDS (3 x 40 KB), depth-2 prefetch with
// counted s_waitcnt vmcnt(10). Split-K=7 (252 blocks); partials accumulated
// via HW f32 atomics into one zeroed [9216][384] buffer.
//
// LDS layout per buffer: A = 128 "pair-lines" (rows 2j,2j+1; 8 x 16B blocks,
// 128 B/line) then B = 192 pair-lines. Slot (j,cc) holds global block
// g = cc ^ (j&7), g = (rowparity<<2)|kblk. Frag reads: stepping 16 rows = 8
// lines keeps j&7 -> offset = base + idx*1024 immediates; 2-way bank aliasing
// max (free, m136). LDS dest is wave-uniform base + lane*16 (m104-safe).
// ---------------------------------------------------------------------------
__global__ __launch_bounds__(512, 2) void k_conv(const _Float16* __restrict__ Xg,
                                                 const _Float16* __restrict__ Wc,
                                                 float* __restrict__ C) {
    __shared__ _Float16 lds[3 * 20480];             // 3 x 40960 B = 122880 B
    const int t = threadIdx.x;
    const int m0 = blockIdx.x * 256;
    const int chunk0 = blockIdx.y * CH32_PER;
    int nch = CH32_TOTAL - chunk0;
    if (nch > CH32_PER) nch = CH32_PER;             // last split: 906

    // ---- staging: 5 slots/thread (2 A + 3 B) ----
    const _Float16* src[5];
    int ldsoff[5];                                  // byte offset within a buffer
#pragma unroll
    for (int p = 0; p < 2; ++p) {
        int s = t + p * 512;                        // A slot 0..1023
        int j = s >> 3, cc = s & 7;
        int g = cc ^ (j & 7);
        int m = m0 + 2 * j + (g >> 2);
        int mrow = m + (m / 288) * 576;             // implicit im2col
        src[p] = Xg + (size_t)mrow * IPAD + (size_t)chunk0 * 32 + (g & 3) * 8;
        ldsoff[p] = s * 16;
    }
#pragma unroll
    for (int p = 0; p < 3; ++p) {
        int s = t + p * 512;                        // B slot 0..1535
        int j = s >> 3, cc = s & 7;
        int g = cc ^ (j & 7);
        int n = 2 * j + (g >> 2);
        src[2 + p] = Wc + (size_t)n * KCONV_PAD + (size_t)chunk0 * 32 + (g & 3) * 8;
        ldsoff[2 + p] = 16384 + s * 16;
    }

    // ---- fragment read offsets ----
    const int lane = t & 63, wv = t >> 6;
    const int wm = wv >> 1, wn = wv & 1;            // 4M x 2N waves
    const int r = lane & 15, q = lane >> 4;
    int row_a = wm * 64 + r;
    int aoff0 = (row_a >> 1) * 128 + ((((row_a & 1) << 2) | q) ^ ((row_a >> 1) & 7)) * 16;
    int row_b = wn * 192 + r;
    int boff0 = 16384 + (row_b >> 1) * 128 +
                ((((row_b & 1) << 2) | q) ^ ((row_b >> 1) & 7)) * 16;

    floatx4 acc[4][12] = {};

    auto stage = [&](int lc, int buf) {
        char* dst = (char*)lds + buf * 40960;
        size_t adv = (size_t)lc * 32;               // 32 halfs = 64 B per chunk
#pragma unroll
        for (int p = 0; p < 5; ++p)
            gload16(src[p] + adv, dst + ldsoff[p]);
    };

    // prologue: chunks 0,1 in flight
    stage(0, 0);
    stage(1, 1);

    int buf = 0;
    for (int lc = 0; lc < nch; ++lc) {
        int pre = lc + 2;  if (pre > nch - 1) pre = nch - 1;     // tail: dummy re-read
        int pbuf = buf + 2; if (pbuf >= 3) pbuf -= 3;
        stage(pre, pbuf);                            // issue loads for lc+2
        asm volatile("s_waitcnt vmcnt(10)" ::: "memory");        // chunk lc landed
        BARRIER();
        const char* cb = (const char*)lds + buf * 40960;
        half8 av[4];
#pragma unroll
        for (int mi = 0; mi < 4; ++mi)
            av[mi] = *(const half8*)(cb + aoff0 + mi * 1024);
#pragma unroll
        for (int ni = 0; ni < 12; ++ni) {
            half8 bv = *(const half8*)(cb + boff0 + ni * 1024);
#pragma unroll
            for (int mi = 0; mi < 4; ++mi)
                acc[mi][ni] = __builtin_amdgcn_mfma_f32_16x16x32_f16(av[mi], bv,
                                                                     acc[mi][ni], 0, 0, 0);
        }
        BARRIER();                                   // all reads of buf done
        buf = (buf + 1 == 3) ? 0 : buf + 1;
    }
    asm volatile("s_waitcnt vmcnt(0)" ::: "memory");

    // C/D layout: col = lane&15, row = (lane>>4)*4 + reg   [m89-verified]
    // HW f32 atomic add (unsafeAtomicAdd -> global_atomic_add_f32)
#pragma unroll
    for (int mi = 0; mi < 4; ++mi)
#pragma unroll
        for (int ni = 0; ni < 12; ++ni) {
            int row = m0 + wm * 64 + mi * 16 + q * 4;
            int col = wn * 192 + ni * 16 + r;
#pragma unroll
            for (int e = 0; e < 4; ++e)
                unsafeAtomicAdd(&C[(size_t)(row + e) * NPAD + col], acc[mi][ni][e]);
        }
}

// ---------------------------------------------------------------------------
// banded D^-1/2 A D^-1/2 (7-diag) + bias + tanh*sigmoid -> f16 Xg (in place)
// Fused S layout: S[m][0..383] = gate1 (tanh), S[m][384..767] = gate2 (sigm).
// ---------------------------------------------------------------------------
__global__ void k_bandact(const float* __restrict__ S,
                          const float* __restrict__ b1, const float* __restrict__ b2,
                          _Float16* __restrict__ Xg) {
    int bm = blockIdx.x;                            // 0..27647
    int m = bm % 864;
    int dm = (m < 3 ? m : 3) + ((863 - m) < 3 ? (863 - m) : 3) + 1;
    for (int o = threadIdx.x; o < 325; o += 256) {
        float g1 = b1[o], g2 = b2[o];
#pragma unroll
        for (int dn = -3; dn <= 3; ++dn) {
            int n = m + dn;
            if (n < 0 || n > 863) continue;
            int dnd = (n < 3 ? n : 3) + ((863 - n) < 3 ? (863 - n) : 3) + 1;
            float a = rsqrtf((float)(dm * dnd));
            size_t off = (size_t)(bm + dn) * NFUSE + o;
            g1 += a * S[off];
            g2 += a * S[off + NPAD];
        }
        float vt = tanhf(g1);
        float vs = 1.f / (1.f + expf(-g2));
        Xg[(size_t)bm * IPAD + o] = (_Float16)(vt * vs);
    }
}

// ---------------------------------------------------------------------------
// conv bias + transpose [m=(b,t)][o] -> out[b][o][t]
// ---------------------------------------------------------------------------
__global__ void k_reduce(const float* __restrict__ Cp, const float* __restrict__ cb,
                         float* __restrict__ out) {
    __shared__ float tile[32][33];
    int b = blockIdx.x, t0 = blockIdx.y * 32, o0 = blockIdx.z * 32;
    int t = threadIdx.x;
    int c = t & 31, r4 = t >> 5;
#pragma unroll
    for (int p = 0; p < 4; ++p) {
        int tt = r4 * 4 + p;
        tile[tt][c] = Cp[(size_t)(b * 288 + t0 + tt) * NPAD + (o0 + c)];
    }
    __syncthreads();
#pragma unroll
    for (int p = 0; p < 4; ++p) {
        int oo = r4 * 4 + p;
        int o = o0 + oo;
        if (o < 325)
            out[((size_t)b * 325 + o) * 288 + t0 + c] = tile[c][oo] + cb[o];
    }
}

// ---------------------------------------------------------------------------
extern "C" void kernel_launch(void* const* d_in, const int* in_sizes, int n_in,
                              void* d_out, int out_size, void* d_ws, size_t ws_size,
                              hipStream_t stream) {
    const float* IF = (const float*)d_in[0];
    const float* x  = (const float*)d_in[1];
    const float* wg[6] = {(const float*)d_in[2],  (const float*)d_in[4],
                          (const float*)d_in[6],  (const float*)d_in[8],
                          (const float*)d_in[10], (const float*)d_in[12]};
    const float* bg[6] = {(const float*)d_in[3],  (const float*)d_in[5],
                          (const float*)d_in[7],  (const float*)d_in[9],
                          (const float*)d_in[11], (const float*)d_in[13]};
    const float* cw  = (const float*)d_in[14];
    const float* cb  = (const float*)d_in[15];
    const int* week  = (const int*)d_in[16];
    const int* hour  = (const int*)d_in[17];
    float* out = (float*)d_out;

    char* ws = (char*)d_ws;
    _Float16* Xg = (_Float16*)(ws + OFF_XG);
    float* S     = (float*)(ws + OFF_S);
    _Float16* Wg = (_Float16*)(ws + OFF_WG);
    _Float16* Wc = (_Float16*)(ws + OFF_WCONV);
    float* Cp    = (float*)(ws + OFF_CPART);   // aliases S (conv phase only)

    k_pack_gcn<<<(6 * NPAD * NPAD) / 256, 256, 0, stream>>>(wg[0], wg[1], wg[2], wg[3],
                                                            wg[4], wg[5], Wg);
    k_pack_conv<<<dim3(NPAD, 11, 19), 256, 0, stream>>>(cw, Wc);
    k_temp<<<(MGCN * IPAD) / 256, 256, 0, stream>>>(IF, x, week, hour, Xg);

    for (int l = 0; l < 3; ++l) {
        k_gemm<<<dim3(MGCN / 128, NFUSE / 128), 256, 0, stream>>>(
            Xg, Wg + (size_t)(2 * l) * NPAD * NPAD, S);
        k_bandact<<<MGCN, 256, 0, stream>>>(S, bg[2 * l], bg[2 * l + 1], Xg);
    }

    hipMemsetAsync(Cp, 0, (size_t)MCONV * NPAD * 4, stream);
    k_conv<<<dim3(MCONV / 256, CONV_SPLITS), 512, 0, stream>>>(Xg, Wc, Cp);

    k_reduce<<<dim3(32, 9, 11), 256, 0, stream>>>(Cp, cb, out);
}